// Round 15
// baseline (192.196 us; speedup 1.0000x reference)
//
#include <hip/hip_runtime.h>
#include <hip/hip_bf16.h>

// Problem constants: x [4,32,32,16,256] -> N=65536 rows, D=256
// embeddings [256, 4096] -> D=256, K=4096
#define NROWS 65536
#define DIM   256
#define KCB   4096
#define CHUNK 32                 // codebook cols per chunk (32 x 512B = 16KB)
#define NCH   (KCB / CHUNK)      // 128 chunks
#define WBUFB 8192               // per-wave half-chunk buffer (16 cols x 512B)
#define NENH_BASE 65536          // nenh f32[4096] after 4 waves x 2 x 8KB

typedef __attribute__((ext_vector_type(8))) short bf16x8;  // 8 bf16, 4 VGPRs
typedef __attribute__((ext_vector_type(4))) float f32x4;

#define WAITV0 asm volatile("s_waitcnt vmcnt(0)" ::: "memory")

__device__ inline short f2bf(float f) {
    __hip_bfloat16 h = __float2bfloat16(f);
    return *reinterpret_cast<short*>(&h);
}

// ---------------------------------------------------------------------------
// Prep 1: tiled transpose E[256][4096] -> ET32[4096][256] (f32) + ETbf (bf16)
// ---------------------------------------------------------------------------
__global__ void prep_transpose(const float* __restrict__ E,
                               float* __restrict__ ET32,
                               ushort* __restrict__ ETbf)
{
    __shared__ float tile[64][65];
    const int kb = blockIdx.x * 64;
    const int db = blockIdx.y * 64;
    const int lo = threadIdx.x & 63;
    const int hi = threadIdx.x >> 6;

#pragma unroll
    for (int i = 0; i < 16; ++i) {
        int d = i * 4 + hi;
        tile[lo][d] = E[(size_t)(db + d) * KCB + kb + lo];
    }
    __syncthreads();
#pragma unroll
    for (int i = 0; i < 16; ++i) {
        int k = i * 4 + hi;
        float v = tile[k][lo];
        size_t off = (size_t)(kb + k) * DIM + db + lo;
        ET32[off] = v;
        ETbf[off] = (ushort)f2bf(v);
    }
}

// ---------------------------------------------------------------------------
// Prep 2: nenh[k] = -0.5*||e_k||^2 (fp32-exact); score = sim + nenh.
// ---------------------------------------------------------------------------
__global__ void prep_enorm(const float* __restrict__ E, float* __restrict__ nenh)
{
    int k = blockIdx.x * 256 + threadIdx.x;
    float s = 0.0f;
#pragma unroll 8
    for (int d = 0; d < DIM; ++d) {
        float v = E[(size_t)d * KCB + k];
        s = fmaf(v, v, s);
    }
    nenh[k] = -0.5f * s;
}

// ---------------------------------------------------------------------------
// vq_argmin: BARRIER-FREE K-loop via private self-staging.
// 256-thread blocks, 4 waves = 2 row-groups (64 rows) x 2 col-halves;
// grid 512 = 2 blocks/CU = 8 waves/CU. R13/R14 post-mortem: the per-chunk
// barrier convoys all 8 waves (reads together -> LDS saturated/matrix idle,
// then MFMAs together) => time = LDS + MFMA summed (2657 cyc/chunk).
// Here each wave stages the 16 cols IT reads into a PRIVATE 2-deep ring
// (stage ct+1 -> own buf; vmcnt(0) own-retire; read; MFMA). No cross-wave
// LDS data flow => no barriers => waves free-run and de-phase; pipes
// overlap: max(MFMA 1242, LDS 792r+512w, L2 ~1170) instead of sum.
// rg-pair waves duplicate-fetch the same cols (2x L2 reads, still under
// the MFMA floor). Swizzle identical to R13 (colL = l15, m = l15&7).
// LDS map/block: [0,64K) = wave*16K + parity*8K bufs; [64K,80K) nenh.
// ---------------------------------------------------------------------------
__shared__ char lds_raw[4 * 2 * WBUFB + 16384];

// Self-stage chunk ct's 16-col half into this wave's buffer PAR.
// 8 issues x 1KB; issue j covers local cols 2j,2j+1. LDS dest linear
// (uniform base + lane*16); XOR swizzle on the global source (both-sides).
template <int PAR>
__device__ __forceinline__ void stage_self(
    const char* __restrict__ etb, const int (&soff)[8], int wbase, int ct)
{
    const char* base = etb + (size_t)ct * (CHUNK * 512);
#pragma unroll
    for (int j = 0; j < 8; ++j) {
        __builtin_amdgcn_global_load_lds(
            (const __attribute__((address_space(1))) unsigned*)(base + soff[j]),
            (__attribute__((address_space(3))) unsigned*)
                (lds_raw + wbase + PAR * WBUFB + j * 1024),
            16, 0, 0);
    }
}

// 32 MFMA (4 independent acc chains, 64 rows), then packed-key argmax.
// key = ord(f32 score), low 12 bits replaced by col (perturbation <=2^-6,
// negligible vs ~0.3 bf16 noise). C/D: col = lane&15, row = (lane>>4)*4+r.
__device__ __forceinline__ void mfma_cluster(
    const bf16x8 (&afrag)[4][8], const bf16x8 (&bfr)[8], float nh,
    unsigned (&best)[4][4], int col)
{
    f32x4 acc[4];
#pragma unroll
    for (int rt = 0; rt < 4; ++rt) acc[rt] = {nh, nh, nh, nh};
#pragma unroll
    for (int kc = 0; kc < 8; ++kc)
#pragma unroll
        for (int rt = 0; rt < 4; ++rt)
            acc[rt] = __builtin_amdgcn_mfma_f32_16x16x32_bf16(
                afrag[rt][kc], bfr[kc], acc[rt], 0, 0, 0);
#pragma unroll
    for (int rt = 0; rt < 4; ++rt)
#pragma unroll
        for (int r = 0; r < 4; ++r) {
            unsigned u = __float_as_uint(acc[rt][r]);
            unsigned key = u ^ ((unsigned)((int)u >> 31) | 0x80000000u);
            unsigned pk = (key & 0xFFFFF000u) | (unsigned)col;
            best[rt][r] = max(best[rt][r], pk);
        }
}

// One chunk, barrier-free: WAITV0 (own ct stages retired; issued a full
// chunk ago, L2 ~300cyc => near-free) -> stage(ct+1 -> other parity) ->
// read own buf -> MFMA. Private ring hazard check: stage PAR^1 while
// reading PAR (disjoint); next overwrite of PAR happens 2 chunks later,
// after this chunk's lgkm-retired reads. No cross-wave dependence.
template <int PAR, bool STG>
__device__ __forceinline__ void chunk_self(
    const char* __restrict__ etb, const int (&soff)[8], int wbase, int ct,
    const int (&boffB)[8], int hc,
    const bf16x8 (&afrag)[4][8], unsigned (&best)[4][4])
{
    WAITV0;
    __builtin_amdgcn_sched_barrier(0);
    if constexpr (STG) stage_self<PAR ^ 1>(etb, soff, wbase, ct + 1);
    float nh = *(const float*)(lds_raw + NENH_BASE + ct * 128 + hc * 4);
    bf16x8 bfr[8];
#pragma unroll
    for (int kc = 0; kc < 8; ++kc)
        bfr[kc] = *(const bf16x8*)(lds_raw + wbase + PAR * WBUFB + boffB[kc]);
    mfma_cluster(afrag, bfr, nh, best, ct * CHUNK + hc);
}

__global__ __launch_bounds__(256, 2)
void vq_argmin(const float* __restrict__ X,       // [65536][256] f32
               const ushort* __restrict__ ETbf,   // [4096][256] bf16
               const float* __restrict__ nenh,    // [4096] = -0.5*||e||^2
               int* __restrict__ idxout)          // [65536]
{
    const int tid  = threadIdx.x;
    const int lane = tid & 63;
    const int wave = tid >> 6;          // 0..3
    const int rg   = wave & 1;          // row-group (64 rows)
    const int h    = wave >> 1;         // col-half (16 cols of each chunk)
    const int l15  = lane & 15;
    const int g    = lane >> 4;         // 0..3
    const int m    = l15 & 7;           // read-side swizzle key
    const int hc   = h * 16 + l15;      // col within chunk
    const int wbase = wave * (2 * WBUFB);
    const long rowbase = (long)blockIdx.x * 128 + rg * 64;
    const char* etb = (const char*)ETbf;

    // A fragments resident in VGPRs: lane holds A[row=l15][k=g*64+kc*8+j],
    // rows rowbase + rt*16 + l15, rt = 0..3 (64 rows/wave). f2bf consumption
    // drains these vmcnt loads before any staging is issued (keeps the
    // manual vmcnt(0) accounting exact).
    bf16x8 afrag[4][8];
#pragma unroll
    for (int rt = 0; rt < 4; ++rt) {
        const float* xr = X + (rowbase + rt * 16 + l15) * DIM;
#pragma unroll
        for (int kc = 0; kc < 8; ++kc) {
            int k0 = g * 64 + kc * 8;
            float4 v0 = *(const float4*)(xr + k0);
            float4 v1 = *(const float4*)(xr + k0 + 4);
            bf16x8 f;
            f[0] = f2bf(v0.x); f[1] = f2bf(v0.y);
            f[2] = f2bf(v0.z); f[3] = f2bf(v0.w);
            f[4] = f2bf(v1.x); f[5] = f2bf(v1.y);
            f[6] = f2bf(v1.z); f[7] = f2bf(v1.w);
            afrag[rt][kc] = f;
        }
    }

    // Per-lane global source offsets for this wave's 16-col half (XOR-swz).
    // Issue j, o = j*1024 + lane*16: local col = o>>9, global col = h*16+local.
    int soff[8];
#pragma unroll
    for (int j = 0; j < 8; ++j) {
        const int o   = j * 1024 + lane * 16;
        const int col = h * 16 + (o >> 9);   // global col within chunk
        const int cph = (o >> 4) & 31;       // physical 16B slot in row
        soff[j] = (col << 9) + ((cph ^ (col & 7)) << 4);
    }

    // LDS read offsets within own buffer: row l15, slot (g*8+kc) ^ m.
    // (Staged LDS holds global slot s^(col&7) at local slot s; col&7 = l15&7.)
    int boffB[8];
#pragma unroll
    for (int kc = 0; kc < 8; ++kc)
        boffB[kc] = l15 * 512 + ((((g << 3) + kc) ^ m) << 4);

    // Prologue: cooperative nenh stage (4KB/wave) + self-stage chunk 0.
#pragma unroll
    for (int j = 0; j < 4; ++j) {
        int o = wave * 4096 + j * 1024 + lane * 16;
        __builtin_amdgcn_global_load_lds(
            (const __attribute__((address_space(1))) unsigned*)((const char*)nenh + o),
            (__attribute__((address_space(3))) unsigned*)
                (lds_raw + NENH_BASE + wave * 4096 + j * 1024),
            16, 0, 0);
    }
    stage_self<0>(etb, soff, wbase, 0);

    unsigned best[4][4];
#pragma unroll
    for (int rt = 0; rt < 4; ++rt)
#pragma unroll
        for (int r = 0; r < 4; ++r) best[rt][r] = 0u;

    // Single barrier: nenh cross-wave visibility. After this, free-run.
    WAITV0;
    __syncthreads();

    // Main loop: 128 chunks, zero barriers. Parity-templated pairs.
    for (int c2 = 0; c2 < 63; ++c2) {
        chunk_self<0, true>(etb, soff, wbase, c2 * 2,     boffB, hc, afrag, best);
        chunk_self<1, true>(etb, soff, wbase, c2 * 2 + 1, boffB, hc, afrag, best);
    }
    chunk_self<0, true >(etb, soff, wbase, 126, boffB, hc, afrag, best);
    chunk_self<1, false>(etb, soff, wbase, 127, boffB, hc, afrag, best);

    // Per-wave reduce across the 16 lanes sharing a row (packed keys), then
    // cross-half merge via LDS (reuses wave buffers; sync first).
    __syncthreads();
    unsigned* mrg = (unsigned*)lds_raw;   // [2][128] packed keys
#pragma unroll
    for (int rt = 0; rt < 4; ++rt) {
#pragma unroll
        for (int r = 0; r < 4; ++r) {
            unsigned pk = best[rt][r];
#pragma unroll
            for (int off = 1; off < 16; off <<= 1)
                pk = max(pk, (unsigned)__shfl_xor((int)pk, off, 64));
            if (l15 == 0) {
                int row = rg * 64 + rt * 16 + g * 4 + r;   // 0..127
                mrg[h * 128 + row] = pk;
            }
        }
    }
    __syncthreads();
    if (tid < 128) {
        unsigned k = max(mrg[tid], mrg[128 + tid]);
        idxout[(long)blockIdx.x * 128 + tid] = (int)(k & 0xFFFu);
    }
}

// ---------------------------------------------------------------------------
// Gather nearest codebook rows (coalesced from ET32) + histogram
// ---------------------------------------------------------------------------
__global__ void vq_gather(const int* __restrict__ idxin,
                          const float* __restrict__ ET32,
                          float* __restrict__ out,
                          unsigned* __restrict__ counts)
{
    const int tid = threadIdx.x;
    const long n  = (long)blockIdx.x * 4 + (tid >> 6);
    const int d4  = tid & 63;
    const int idx = idxin[n];
    float4 v = *(const float4*)(ET32 + (size_t)idx * DIM + d4 * 4);
    *(float4*)(out + n * DIM + d4 * 4) = v;
    if (d4 == 0) atomicAdd(&counts[idx], 1u);
}

// ---------------------------------------------------------------------------
// Perplexity = exp(-sum p*log(p+1e-10)), p = counts/N
// ---------------------------------------------------------------------------
__global__ void vq_perplexity(const unsigned* __restrict__ counts, float* __restrict__ outp)
{
    __shared__ float wsum[4];
    const int tid = threadIdx.x;
    float s = 0.0f;
    for (int k = tid; k < KCB; k += 256) {
        float p = (float)counts[k] * (1.0f / (float)NROWS);
        s += p * logf(p + 1e-10f);
    }
#pragma unroll
    for (int off = 32; off >= 1; off >>= 1) s += __shfl_down(s, off, 64);
    if ((tid & 63) == 0) wsum[tid >> 6] = s;
    __syncthreads();
    if (tid == 0) outp[0] = expf(-(wsum[0] + wsum[1] + wsum[2] + wsum[3]));
}

// ---------------------------------------------------------------------------
extern "C" void kernel_launch(void* const* d_in, const int* in_sizes, int n_in,
                              void* d_out, int out_size, void* d_ws, size_t ws_size,
                              hipStream_t stream)
{
    const float* X = (const float*)d_in[0];
    const float* E = (const float*)d_in[1];
    float* out = (float*)d_out;

    char* ws = (char*)d_ws;
    float*    ET32   = (float*)ws;                                   // 4 MB
    ushort*   ETbf   = (ushort*)(ws + (size_t)KCB * DIM * 4);        // 2 MB
    float*    nenh   = (float*)(ws + (size_t)KCB * DIM * 6);         // 16 KB
    int*      idxbuf = (int*)(ws + (size_t)KCB * DIM * 6 + KCB * 4); // 256 KB
    unsigned* counts = (unsigned*)(ws + (size_t)KCB * DIM * 6 + KCB * 4 + NROWS * 4); // 16 KB

    hipMemsetAsync(counts, 0, KCB * sizeof(unsigned), stream);

    prep_transpose<<<dim3(KCB / 64, DIM / 64), dim3(256), 0, stream>>>(E, ET32, ETbf);
    prep_enorm<<<KCB / 256, dim3(256), 0, stream>>>(E, nenh);
    vq_argmin<<<NROWS / 128, dim3(256), 0, stream>>>(X, ETbf, nenh, idxbuf);
    vq_gather<<<NROWS / 4, dim3(256), 0, stream>>>(idxbuf, ET32, out, counts);
    vq_perplexity<<<1, dim3(256), 0, stream>>>(counts, out + (size_t)NROWS * DIM);
}